// Round 1
// baseline (641.028 us; speedup 1.0000x reference)
//
#include <hip/hip_runtime.h>
#include <stdint.h>

#define NN 100000
#define NE 1600000
#define NG 1000
#define FIN 128
#define DIM 32
#define NC 10
#define CAP 64
#define OVF_CAP 65536

typedef unsigned int u32;

// ---------------- zero ----------------
__global__ void k_zero(u32* __restrict__ p, int n) {
    int i = blockIdx.x * blockDim.x + threadIdx.x;
    if (i < n) p[i] = 0u;
}

// ---------------- bucket fill: dst-bucketed edge list ----------------
__global__ void k_fill(const int* __restrict__ ei, const float* __restrict__ ew,
                       int* __restrict__ deg, uint2* __restrict__ edges,
                       int* __restrict__ ovfCnt, int4* __restrict__ ovf) {
    int e = blockIdx.x * blockDim.x + threadIdx.x;
    if (e >= NE) return;
    int s = ei[e];
    int d = ei[NE + e];
    float w = ew[e];
    int slot = atomicAdd(&deg[d], 1);
    if (slot < CAP) {
        edges[(size_t)d * CAP + slot] = make_uint2((u32)s, __float_as_uint(w));
    } else {
        int k = atomicAdd(ovfCnt, 1);
        if (k < OVF_CAP) ovf[k] = make_int4(d, s, __float_as_int(w), 0);
    }
}

// ---------------- layer-1 matmul: x[N,128] -> yrel = x@Wrel, aggi = x@Wroot + brel ----------------
__global__ __launch_bounds__(256) void k_mm1(const float* __restrict__ x,
        const float* __restrict__ Wrel, const float* __restrict__ brel,
        const float* __restrict__ Wroot,
        float* __restrict__ yrel, float* __restrict__ aggi) {
    __shared__ float wr[FIN * DIM];      // 16 KB
    __shared__ float wo[FIN * DIM];      // 16 KB
    __shared__ float xs[32 * 132];       // 32 rows, stride 132 (pad 4 -> conflict-free)
    int tid = threadIdx.x;
    for (int i = tid; i < FIN * DIM / 4; i += 256) {
        ((float4*)wr)[i] = ((const float4*)Wrel)[i];
        ((float4*)wo)[i] = ((const float4*)Wroot)[i];
    }
    int l  = tid & 7;    // 8 lanes per node, 4 output cols each
    int ng = tid >> 3;   // node-in-block 0..31
    float4 b4 = ((const float4*)brel)[l];
    for (int base = blockIdx.x * 32; base < NN; base += gridDim.x * 32) {
        __syncthreads();
        for (int i = tid; i < 32 * FIN / 4; i += 256) {
            int r = i >> 5, c = i & 31;
            int node = base + r;
            float4 v = make_float4(0.f, 0.f, 0.f, 0.f);
            if (node < NN) v = ((const float4*)x)[(size_t)node * (FIN / 4) + c];
            ((float4*)xs)[r * 33 + c] = v;
        }
        __syncthreads();
        int node = base + ng;
        if (node >= NN) continue;
        const float* xrow = xs + ng * 132;
        float4 aR = make_float4(0.f, 0.f, 0.f, 0.f);
        float4 aO = make_float4(0.f, 0.f, 0.f, 0.f);
        #pragma unroll 4
        for (int k = 0; k < FIN; ++k) {
            float xv = xrow[k];
            float4 w1 = ((const float4*)wr)[k * 8 + l];
            float4 w2 = ((const float4*)wo)[k * 8 + l];
            aR.x += xv * w1.x; aR.y += xv * w1.y; aR.z += xv * w1.z; aR.w += xv * w1.w;
            aO.x += xv * w2.x; aO.y += xv * w2.y; aO.z += xv * w2.z; aO.w += xv * w2.w;
        }
        ((float4*)yrel)[(size_t)node * 8 + l] = aR;
        aO.x += b4.x; aO.y += b4.y; aO.z += b4.z; aO.w += b4.w;
        ((float4*)aggi)[(size_t)node * 8 + l] = aO;
    }
}

// ---------------- layers 2-5 matmul: in (pre-relu) -> yrel = relu(in)@Wrel, aggi = relu(in)@Wroot + brel ----------------
__global__ __launch_bounds__(256) void k_mm_small(const float* __restrict__ in,
        const float* __restrict__ Wrel, const float* __restrict__ brel,
        const float* __restrict__ Wroot,
        float* __restrict__ yrel, float* __restrict__ aggi) {
    __shared__ float wr[DIM * DIM];
    __shared__ float wo[DIM * DIM];
    __shared__ float hs[32 * 36];        // stride 36: conflict-free broadcast read
    int tid = threadIdx.x;
    for (int i = tid; i < DIM * DIM / 4; i += 256) {
        ((float4*)wr)[i] = ((const float4*)Wrel)[i];
        ((float4*)wo)[i] = ((const float4*)Wroot)[i];
    }
    int l  = tid & 7;
    int ng = tid >> 3;
    float4 b4 = ((const float4*)brel)[l];
    for (int base = blockIdx.x * 32; base < NN; base += gridDim.x * 32) {
        __syncthreads();
        {
            int i = tid;                                // 32*32/4 == 256: one float4 per thread
            int r = i >> 3, c = i & 7;
            int node = base + r;
            float4 v = make_float4(0.f, 0.f, 0.f, 0.f);
            if (node < NN) {
                v = ((const float4*)in)[(size_t)node * 8 + c];
                v.x = fmaxf(v.x, 0.f); v.y = fmaxf(v.y, 0.f);
                v.z = fmaxf(v.z, 0.f); v.w = fmaxf(v.w, 0.f);
            }
            ((float4*)hs)[r * 9 + c] = v;
        }
        __syncthreads();
        int node = base + ng;
        if (node >= NN) continue;
        const float* hrow = hs + ng * 36;
        float4 aR = make_float4(0.f, 0.f, 0.f, 0.f);
        float4 aO = make_float4(0.f, 0.f, 0.f, 0.f);
        #pragma unroll
        for (int k = 0; k < DIM; ++k) {
            float hv = hrow[k];
            float4 w1 = ((const float4*)wr)[k * 8 + l];
            float4 w2 = ((const float4*)wo)[k * 8 + l];
            aR.x += hv * w1.x; aR.y += hv * w1.y; aR.z += hv * w1.z; aR.w += hv * w1.w;
            aO.x += hv * w2.x; aO.y += hv * w2.y; aO.z += hv * w2.z; aO.w += hv * w2.w;
        }
        ((float4*)yrel)[(size_t)node * 8 + l] = aR;
        aO.x += b4.x; aO.y += b4.y; aO.z += b4.z; aO.w += b4.w;
        ((float4*)aggi)[(size_t)node * 8 + l] = aO;
    }
}

// ---------------- gather: agg[n] += sum_j w_j * y[src_j]  (race-free, no atomics) ----------------
__global__ __launch_bounds__(256) void k_gather(const float* __restrict__ y,
        const uint2* __restrict__ edges, const int* __restrict__ deg,
        const int* __restrict__ ovfCnt, const int4* __restrict__ ovf,
        float* __restrict__ agg) {
    int tid = threadIdx.x;
    int lane = tid & 31;                 // feature dim
    int node = blockIdx.x * 8 + (tid >> 5);
    if (node >= NN) return;
    int dg  = deg[node];
    int dcl = min(dg, CAP);
    const uint2* eb = edges + (size_t)node * CAP;
    float acc = 0.f;
    int j = 0;
    for (; j + 4 <= dcl; j += 4) {
        uint2 e0 = eb[j], e1 = eb[j + 1], e2 = eb[j + 2], e3 = eb[j + 3];
        float v0 = y[(size_t)e0.x * DIM + lane];
        float v1 = y[(size_t)e1.x * DIM + lane];
        float v2 = y[(size_t)e2.x * DIM + lane];
        float v3 = y[(size_t)e3.x * DIM + lane];
        acc += __uint_as_float(e0.y) * v0;
        acc += __uint_as_float(e1.y) * v1;
        acc += __uint_as_float(e2.y) * v2;
        acc += __uint_as_float(e3.y) * v3;
    }
    for (; j < dcl; ++j) {
        uint2 e = eb[j];
        acc += __uint_as_float(e.y) * y[(size_t)e.x * DIM + lane];
    }
    int ov = *ovfCnt;
    if (ov > 0) {                        // (practically never taken; keeps CAP safe)
        ov = min(ov, OVF_CAP);
        for (int k = 0; k < ov; ++k) {
            int4 o = ovf[k];
            if (o.x == node) acc += __int_as_float(o.z) * y[(size_t)o.y * DIM + lane];
        }
    }
    agg[(size_t)node * DIM + lane] += acc;
}

// ---------------- fallback scatter (atomics) if ws too small for buckets ----------------
__global__ __launch_bounds__(256) void k_scatter_atomic(const float* __restrict__ y,
        const int* __restrict__ ei, const float* __restrict__ ew,
        float* __restrict__ agg) {
    int t = blockIdx.x * blockDim.x + threadIdx.x;
    int e = t >> 5;
    int lane = t & 31;
    if (e >= NE) return;
    int s = ei[e], d = ei[NE + e];
    float w = ew[e];
    atomicAdd(&agg[(size_t)d * DIM + lane], w * y[(size_t)s * DIM + lane]);
}

// ---------------- pool: g[batch[n]] += relu(h[n]); batch is sorted -> segmented running sum ----------------
#define STRIP 32
__global__ __launch_bounds__(256) void k_pool(const float* __restrict__ h,
        const int* __restrict__ batch, float* __restrict__ g) {
    int tid = threadIdx.x;
    int lane = tid & 31;
    int grp = blockIdx.x * 8 + (tid >> 5);
    int start = grp * STRIP;
    if (start >= NN) return;
    int end = min(start + STRIP, NN);
    int curb = batch[start];
    float run = 0.f;
    for (int n = start; n < end; ++n) {
        int b = batch[n];
        if (b != curb) {
            atomicAdd(&g[(size_t)curb * DIM + lane], run);
            run = 0.f; curb = b;
        }
        run += fmaxf(h[(size_t)n * DIM + lane], 0.f);
    }
    atomicAdd(&g[(size_t)curb * DIM + lane], run);
}

// ---------------- head: relu(g@W1+b1) @ W2 + b2 -> log_softmax ----------------
__global__ __launch_bounds__(64) void k_head(const float* __restrict__ g,
        const float* __restrict__ W1, const float* __restrict__ b1,
        const float* __restrict__ W2, const float* __restrict__ b2,
        float* __restrict__ out) {
    __shared__ float gs[DIM];
    __shared__ float a1[DIM];
    __shared__ float lg[NC];
    int t = threadIdx.x;
    int gr = blockIdx.x;
    if (t < DIM) gs[t] = g[(size_t)gr * DIM + t];
    __syncthreads();
    if (t < DIM) {
        float a = b1[t];
        #pragma unroll
        for (int k = 0; k < DIM; ++k) a += gs[k] * W1[k * DIM + t];
        a1[t] = fmaxf(a, 0.f);
    }
    __syncthreads();
    if (t < NC) {
        float a = b2[t];
        #pragma unroll
        for (int k = 0; k < DIM; ++k) a += a1[k] * W2[k * NC + t];
        lg[t] = a;
    }
    __syncthreads();
    if (t == 0) {
        float m = lg[0];
        for (int c = 1; c < NC; ++c) m = fmaxf(m, lg[c]);
        float s = 0.f;
        for (int c = 0; c < NC; ++c) s += expf(lg[c] - m);
        float ls = m + logf(s);
        for (int c = 0; c < NC; ++c) out[(size_t)gr * NC + c] = lg[c] - ls;
    }
}

extern "C" void kernel_launch(void* const* d_in, const int* in_sizes, int n_in,
                              void* d_out, int out_size, void* d_ws, size_t ws_size,
                              hipStream_t stream) {
    const float* x    = (const float*)d_in[0];
    const int*   ei   = (const int*)d_in[1];
    const int*   batch= (const int*)d_in[2];
    const float* ew   = (const float*)d_in[3];
    const float* Wrel[5]  = {(const float*)d_in[4],  (const float*)d_in[7],  (const float*)d_in[10], (const float*)d_in[13], (const float*)d_in[16]};
    const float* brel[5]  = {(const float*)d_in[5],  (const float*)d_in[8],  (const float*)d_in[11], (const float*)d_in[14], (const float*)d_in[17]};
    const float* Wroot[5] = {(const float*)d_in[6],  (const float*)d_in[9],  (const float*)d_in[12], (const float*)d_in[15], (const float*)d_in[18]};
    const float* W1 = (const float*)d_in[19];
    const float* b1 = (const float*)d_in[20];
    const float* W2 = (const float*)d_in[21];
    const float* b2 = (const float*)d_in[22];
    float* out = (float*)d_out;

    char* ws = (char*)d_ws;

    // main layout
    const size_t off_deg   = 0;                               // NN*4      = 400000
    const size_t off_ovfc  = 400000;                          // 16 B
    const size_t off_g     = 400016;                          // NG*DIM*4  = 128000
    const size_t zero_end  = 528016;                          // deg+ovfc+g zeroed in one pass
    const size_t off_edges = 528016;                          // NN*CAP*8  = 51,200,000
    const size_t off_ovf   = off_edges + (size_t)NN * CAP * 8;
    const size_t off_A     = off_ovf + (size_t)OVF_CAP * 16;
    const size_t off_B     = off_A + (size_t)NN * DIM * 4;
    const size_t off_C     = off_B + (size_t)NN * DIM * 4;
    const size_t need      = off_C + (size_t)NN * DIM * 4;    // ~91.2 MB

    if (ws_size >= need) {
        int*   deg  = (int*)(ws + off_deg);
        int*   ovfc = (int*)(ws + off_ovfc);
        float* g    = (float*)(ws + off_g);
        uint2* edges= (uint2*)(ws + off_edges);
        int4*  ovf  = (int4*)(ws + off_ovf);
        float* A    = (float*)(ws + off_A);
        float* B    = (float*)(ws + off_B);
        float* C    = (float*)(ws + off_C);

        int zcount = (int)(zero_end / 4);
        k_zero<<<(zcount + 255) / 256, 256, 0, stream>>>((u32*)ws, zcount);
        k_fill<<<(NE + 255) / 256, 256, 0, stream>>>(ei, ew, deg, edges, ovfc, ovf);

        k_mm1<<<1024, 256, 0, stream>>>(x, Wrel[0], brel[0], Wroot[0], B, A);
        k_gather<<<12500, 256, 0, stream>>>(B, edges, deg, ovfc, ovf, A);
        float* cur = A; float* nxt = C;
        for (int L = 1; L < 5; ++L) {
            k_mm_small<<<1024, 256, 0, stream>>>(cur, Wrel[L], brel[L], Wroot[L], B, nxt);
            k_gather<<<12500, 256, 0, stream>>>(B, edges, deg, ovfc, ovf, nxt);
            float* tmp = cur; cur = nxt; nxt = tmp;
        }
        k_pool<<<391, 256, 0, stream>>>(cur, batch, g);
        k_head<<<NG, 64, 0, stream>>>(g, W1, b1, W2, b2, out);
    } else {
        // fallback: atomic scatter, minimal scratch (~38.5 MB)
        float* g = (float*)ws;
        float* A = (float*)(ws + 128000);
        float* B = A + (size_t)NN * DIM;
        float* C = B + (size_t)NN * DIM;

        k_zero<<<(NG * DIM + 255) / 256, 256, 0, stream>>>((u32*)g, NG * DIM);
        k_mm1<<<1024, 256, 0, stream>>>(x, Wrel[0], brel[0], Wroot[0], B, A);
        int sblocks = (NE * 32 + 255) / 256;
        k_scatter_atomic<<<sblocks, 256, 0, stream>>>(B, ei, ew, A);
        float* cur = A; float* nxt = C;
        for (int L = 1; L < 5; ++L) {
            k_mm_small<<<1024, 256, 0, stream>>>(cur, Wrel[L], brel[L], Wroot[L], B, nxt);
            k_scatter_atomic<<<sblocks, 256, 0, stream>>>(B, ei, ew, nxt);
            float* tmp = cur; cur = nxt; nxt = tmp;
        }
        k_pool<<<391, 256, 0, stream>>>(cur, batch, g);
        k_head<<<NG, 64, 0, stream>>>(g, W1, b1, W2, b2, out);
    }
}